// Round 9
// baseline (8713.987 us; speedup 1.0000x reference)
//
#include <hip/hip_runtime.h>

// Problem constants (from reference): B=32, T=2048, D_IN=D_OUT=512, fp32.
constexpr int B = 32, T = 2048, D = 512;

typedef float f32x4 __attribute__((ext_vector_type(4)));

// ---------------- Kernel 1: xw = x @ W + b, written in-place into d_out ----
__global__ __launch_bounds__(256) void xw_gemm(
    const float* __restrict__ A, const float* __restrict__ W,
    const float* __restrict__ bias, float* __restrict__ C) {
  __shared__ float As[16][68];
  __shared__ float Bs[16][68];
  const int tid = threadIdx.x;
  const int M0 = blockIdx.y * 64, N0 = blockIdx.x * 64;
  const int tn = tid & 15, tm = tid >> 4;
  const int rA = tid >> 2, kA = (tid & 3) << 2;
  const int kB = tid >> 4, nB = (tid & 15) << 2;
  float acc[4][4] = {};
  for (int k0 = 0; k0 < 512; k0 += 16) {
    float4 a4 = *(const float4*)&A[(size_t)(M0 + rA) * 512 + k0 + kA];
    As[kA + 0][rA] = a4.x;
    As[kA + 1][rA] = a4.y;
    As[kA + 2][rA] = a4.z;
    As[kA + 3][rA] = a4.w;
    *(float4*)&Bs[kB][nB] = *(const float4*)&W[(size_t)(k0 + kB) * 512 + N0 + nB];
    __syncthreads();
#pragma unroll
    for (int k = 0; k < 16; ++k) {
      float a0 = As[k][tm * 4 + 0], a1 = As[k][tm * 4 + 1];
      float a2 = As[k][tm * 4 + 2], a3 = As[k][tm * 4 + 3];
      float b0 = Bs[k][tn * 4 + 0], b1 = Bs[k][tn * 4 + 1];
      float b2 = Bs[k][tn * 4 + 2], b3 = Bs[k][tn * 4 + 3];
      acc[0][0] += a0 * b0; acc[0][1] += a0 * b1; acc[0][2] += a0 * b2; acc[0][3] += a0 * b3;
      acc[1][0] += a1 * b0; acc[1][1] += a1 * b1; acc[1][2] += a1 * b2; acc[1][3] += a1 * b3;
      acc[2][0] += a2 * b0; acc[2][1] += a2 * b1; acc[2][2] += a2 * b2; acc[2][3] += a2 * b3;
      acc[3][0] += a3 * b0; acc[3][1] += a3 * b1; acc[3][2] += a3 * b2; acc[3][3] += a3 * b3;
    }
    __syncthreads();
  }
#pragma unroll
  for (int i = 0; i < 4; ++i) {
    const size_t row = (size_t)(M0 + tm * 4 + i);
    float4 v;
    v.x = acc[i][0] + bias[N0 + tn * 4 + 0];
    v.y = acc[i][1] + bias[N0 + tn * 4 + 1];
    v.z = acc[i][2] + bias[N0 + tn * 4 + 2];
    v.w = acc[i][3] + bias[N0 + tn * 4 + 3];
    *(float4*)&C[row * 512 + N0 + tn * 4] = v;
  }
}

// ---------------- Kernel 2: clique scan, W truly pinned in VGPRs -----------
// 64 blocks x 512 threads = 16 cliques x 4 blocks. Clique cq owns batches
// {2cq, 2cq+1}; block role owns cols [128*role,+128). Thread (cg=tid>>4,
// ks=tid&15): 4 cols x 32 k; W = 32 f32x4 pinned via asm "+v" barriers
// (blocks rematerialization — the r5/r6/r7 VGPR_Count<array-size defect).
// Per round: 2 staggered phases (one per batch); h exchange via relaxed
// agent atomics + 4-band self-tagging (proven r4/r5/r7). LDS h is
// XOR-swizzled (2-way conflicts = free). One barrier per phase.
constexpr int NBLK = 64, NTHR = 512;

__device__ __forceinline__ float ld_f(const float* p) {
  return __hip_atomic_load(p, __ATOMIC_RELAXED, __HIP_MEMORY_SCOPE_AGENT);
}
__device__ __forceinline__ void st_f(float* p, float v) {
  __hip_atomic_store(p, v, __ATOMIC_RELAXED, __HIP_MEMORY_SCOPE_AGENT);
}
__device__ __forceinline__ int chk4(f32x4 v, float off) {
  return (fabsf(v[0] - off) < 1.5f) & (fabsf(v[1] - off) < 1.5f) &
         (fabsf(v[2] - off) < 1.5f) & (fabsf(v[3] - off) < 1.5f);
}

__global__ __launch_bounds__(NTHR, 2) void rnn_scan(
    float* __restrict__ out, const float* __restrict__ Wrec,
    float* __restrict__ xbuf) {
  __shared__ float h_s[2][2][512];  // [batch-in-clique][parity][k swizzled]
  const int blk = blockIdx.x;
  const int cq = blk >> 2;   // clique 0..15
  const int role = blk & 3;  // col quarter
  const int tid = threadIdx.x;
  const int ks = tid & 15;   // k-slice (32 k)
  const int cg = tid >> 4;   // col group 0..31 (4 cols)
  const int colbase = role * 128 + cg * 4;
  const int kb = ks * 32;
  const int gbA = cq * 2, gbB = gbA + 1;
  const int swzT = (ks & 7) << 2;              // h-read swizzle (const/thread)
  const int swzF = ((colbase >> 5) & 7) << 2;  // finalize-write swizzle

  // ---- W slice into registers, PINNED (asm barrier defeats remat) ----
  f32x4 wv[32];
#pragma unroll
  for (int i = 0; i < 32; ++i)
    wv[i] = *(const f32x4*)&Wrec[(size_t)(kb + i) * D + colbase];
#pragma unroll
  for (int i = 0; i < 32; ++i) asm volatile("" : "+v"(wv[i]));

  float* xc = xbuf + (size_t)cq * 2048;  // [s][parity][role(4)][128]
  const float OF[4] = {3.f, 9.f, -3.f, -9.f};
  const bool fin = (ks == 0);
  // pollers: phase A = tid<96 (waves 0..1), phase B = tid in [128,224)
  const bool isPA = (tid < 96), isPB = (tid >= 128 && tid < 224);
  int prr = 0, pg = 0, pgx = 0;
  if (isPA | isPB) {
    const int p = isPA ? tid : (tid - 128);  // 0..95
    const int pi = p >> 5;                   // foreign producer 0..2
    prr = pi + (pi >= role);                 // actual producer role
    pg = (p & 31) * 4;                       // col offset within producer
    const int gk = prr * 128 + pg;           // global k index staged
    pgx = gk ^ (((gk >> 5) & 7) << 2);       // swizzled LDS index
  }

  // ---- t = 0: h0 = tanh(xw_0); own h_s chunk; publish parity 0, band OF[0]
  if (fin) {
#pragma unroll
    for (int s = 0; s < 2; ++s) {
      const size_t o = ((size_t)(gbA + s) * T) * D + colbase;
      const f32x4 x0 = *(const f32x4*)&out[o];
      f32x4 h;
      h[0] = tanhf(x0[0]); h[1] = tanhf(x0[1]);
      h[2] = tanhf(x0[2]); h[3] = tanhf(x0[3]);
      *(f32x4*)&out[o] = h;
      *(f32x4*)&h_s[s][0][colbase ^ swzF] = h;
      float* d = &xc[(s * 2 + 0) * 512 + role * 128 + cg * 4];
      st_f(d + 0, h[0] + OF[0]); st_f(d + 1, h[1] + OF[0]);
      st_f(d + 2, h[2] + OF[0]); st_f(d + 3, h[3] + OF[0]);
    }
  }
  // initial pre-issued poll loads (may read 0 / stale — re-polled in-loop)
  f32x4 eA = {0, 0, 0, 0}, eB = {0, 0, 0, 0};
  if (isPA) {
    const float* p = &xc[(0 * 2 + 0) * 512 + prr * 128 + pg];
    eA[0] = ld_f(p); eA[1] = ld_f(p + 1); eA[2] = ld_f(p + 2); eA[3] = ld_f(p + 3);
  }
  if (isPB) {
    const float* p = &xc[(1 * 2 + 0) * 512 + prr * 128 + pg];
    eB[0] = ld_f(p); eB[1] = ld_f(p + 1); eB[2] = ld_f(p + 2); eB[3] = ld_f(p + 3);
  }

  for (int r = 1; r < T; ++r) {
    const int pv = (r - 1) & 1, pw = r & 1;
    const float offR = OF[(r - 1) & 3], offW = OF[r & 3];

    // ================= phase A (batch gbA) =================
    f32x4 xwA = {0, 0, 0, 0};
    if (fin) xwA = *(const f32x4*)&out[((size_t)gbA * T + r) * D + colbase];
    if (isPA) {
      const float* sp = &xc[(0 * 2 + pv) * 512 + prr * 128 + pg];
      int ok = chk4(eA, offR);
      while (!__all(ok)) {
        eA[0] = ld_f(sp); eA[1] = ld_f(sp + 1);
        eA[2] = ld_f(sp + 2); eA[3] = ld_f(sp + 3);
        ok = chk4(eA, offR);
      }
      *(f32x4*)&h_s[0][pv][pgx] = eA - offR;
      const float* np = &xc[(0 * 2 + pw) * 512 + prr * 128 + pg];
      eA[0] = ld_f(np); eA[1] = ld_f(np + 1);
      eA[2] = ld_f(np + 2); eA[3] = ld_f(np + 3);
    }
    __syncthreads();
    {
      f32x4 hv[8];
#pragma unroll
      for (int i4 = 0; i4 < 8; ++i4)
        hv[i4] = *(const f32x4*)&h_s[0][pv][(kb + 4 * i4) ^ swzT];
      f32x4 acc = {0, 0, 0, 0};
#pragma unroll
      for (int i4 = 0; i4 < 8; ++i4) {
#pragma unroll
        for (int j = 0; j < 4; ++j) {
          const float hj = hv[i4][j];
          acc[0] += wv[i4 * 4 + j][0] * hj;
          acc[1] += wv[i4 * 4 + j][1] * hj;
          acc[2] += wv[i4 * 4 + j][2] * hj;
          acc[3] += wv[i4 * 4 + j][3] * hj;
        }
      }
#pragma unroll
      for (int m = 1; m < 16; m <<= 1) {
        acc[0] += __shfl_xor(acc[0], m);
        acc[1] += __shfl_xor(acc[1], m);
        acc[2] += __shfl_xor(acc[2], m);
        acc[3] += __shfl_xor(acc[3], m);
      }
      if (fin) {
        f32x4 h;
        h[0] = tanhf(acc[0] + xwA[0]); h[1] = tanhf(acc[1] + xwA[1]);
        h[2] = tanhf(acc[2] + xwA[2]); h[3] = tanhf(acc[3] + xwA[3]);
        *(f32x4*)&out[((size_t)gbA * T + r) * D + colbase] = h;
        *(f32x4*)&h_s[0][pw][colbase ^ swzF] = h;
        float* d = &xc[(0 * 2 + pw) * 512 + role * 128 + cg * 4];
        st_f(d + 0, h[0] + offW); st_f(d + 1, h[1] + offW);
        st_f(d + 2, h[2] + offW); st_f(d + 3, h[3] + offW);
      }
    }

    // ================= phase B (batch gbB) =================
    f32x4 xwB = {0, 0, 0, 0};
    if (fin) xwB = *(const f32x4*)&out[((size_t)gbB * T + r) * D + colbase];
    if (isPB) {
      const float* sp = &xc[(1 * 2 + pv) * 512 + prr * 128 + pg];
      int ok = chk4(eB, offR);
      while (!__all(ok)) {
        eB[0] = ld_f(sp); eB[1] = ld_f(sp + 1);
        eB[2] = ld_f(sp + 2); eB[3] = ld_f(sp + 3);
        ok = chk4(eB, offR);
      }
      *(f32x4*)&h_s[1][pv][pgx] = eB - offR;
      const float* np = &xc[(1 * 2 + pw) * 512 + prr * 128 + pg];
      eB[0] = ld_f(np); eB[1] = ld_f(np + 1);
      eB[2] = ld_f(np + 2); eB[3] = ld_f(np + 3);
    }
    __syncthreads();
    {
      f32x4 hv[8];
#pragma unroll
      for (int i4 = 0; i4 < 8; ++i4)
        hv[i4] = *(const f32x4*)&h_s[1][pv][(kb + 4 * i4) ^ swzT];
      f32x4 acc = {0, 0, 0, 0};
#pragma unroll
      for (int i4 = 0; i4 < 8; ++i4) {
#pragma unroll
        for (int j = 0; j < 4; ++j) {
          const float hj = hv[i4][j];
          acc[0] += wv[i4 * 4 + j][0] * hj;
          acc[1] += wv[i4 * 4 + j][1] * hj;
          acc[2] += wv[i4 * 4 + j][2] * hj;
          acc[3] += wv[i4 * 4 + j][3] * hj;
        }
      }
#pragma unroll
      for (int m = 1; m < 16; m <<= 1) {
        acc[0] += __shfl_xor(acc[0], m);
        acc[1] += __shfl_xor(acc[1], m);
        acc[2] += __shfl_xor(acc[2], m);
        acc[3] += __shfl_xor(acc[3], m);
      }
      if (fin) {
        f32x4 h;
        h[0] = tanhf(acc[0] + xwB[0]); h[1] = tanhf(acc[1] + xwB[1]);
        h[2] = tanhf(acc[2] + xwB[2]); h[3] = tanhf(acc[3] + xwB[3]);
        *(f32x4*)&out[((size_t)gbB * T + r) * D + colbase] = h;
        *(f32x4*)&h_s[1][pw][colbase ^ swzF] = h;
        float* d = &xc[(1 * 2 + pw) * 512 + role * 128 + cg * 4];
        st_f(d + 0, h[0] + offW); st_f(d + 1, h[1] + offW);
        st_f(d + 2, h[2] + offW); st_f(d + 3, h[3] + offW);
      }
    }
  }
}

extern "C" void kernel_launch(void* const* d_in, const int* in_sizes, int n_in,
                              void* d_out, int out_size, void* d_ws, size_t ws_size,
                              hipStream_t stream) {
  const float* x = (const float*)d_in[0];
  const float* W = (const float*)d_in[1];
  const float* Wrec = (const float*)d_in[2];
  const float* bias = (const float*)d_in[3];
  float* out = (float*)d_out;

  // xw + bias straight into d_out (row = b*T+t matches [B][T][D]).
  xw_gemm<<<dim3(D / 64, (B * T) / 64), 256, 0, stream>>>(x, W, bias, out);

  // xbuf: 16 cliques x [2 batches][2 parities][4 roles][128] = 128 KB.
  // Zeroed every launch (zero is in no band) -> deterministic replays.
  hipMemsetAsync(d_ws, 0, (size_t)16 * 2048 * sizeof(float), stream);
  float* xbuf = (float*)d_ws;

  void* args[] = {(void*)&out, (void*)&Wrec, (void*)&xbuf};
  hipLaunchCooperativeKernel(reinterpret_cast<void*>(rnn_scan), dim3(NBLK),
                             dim3(NTHR), args, 0, stream);
}

// Round 10
// 7369.360 us; speedup vs baseline: 1.1825x; 1.1825x over previous
//
#include <hip/hip_runtime.h>

// Problem constants (from reference): B=32, T=2048, D_IN=D_OUT=512, fp32.
constexpr int B = 32, T = 2048, D = 512;

typedef float f32x4 __attribute__((ext_vector_type(4)));

// ---------------- Kernel 1: xw = x @ W + b, written in-place into d_out ----
__global__ __launch_bounds__(256) void xw_gemm(
    const float* __restrict__ A, const float* __restrict__ W,
    const float* __restrict__ bias, float* __restrict__ C) {
  __shared__ float As[16][68];
  __shared__ float Bs[16][68];
  const int tid = threadIdx.x;
  const int M0 = blockIdx.y * 64, N0 = blockIdx.x * 64;
  const int tn = tid & 15, tm = tid >> 4;
  const int rA = tid >> 2, kA = (tid & 3) << 2;
  const int kB = tid >> 4, nB = (tid & 15) << 2;
  float acc[4][4] = {};
  for (int k0 = 0; k0 < 512; k0 += 16) {
    float4 a4 = *(const float4*)&A[(size_t)(M0 + rA) * 512 + k0 + kA];
    As[kA + 0][rA] = a4.x;
    As[kA + 1][rA] = a4.y;
    As[kA + 2][rA] = a4.z;
    As[kA + 3][rA] = a4.w;
    *(float4*)&Bs[kB][nB] = *(const float4*)&W[(size_t)(k0 + kB) * 512 + N0 + nB];
    __syncthreads();
#pragma unroll
    for (int k = 0; k < 16; ++k) {
      float a0 = As[k][tm * 4 + 0], a1 = As[k][tm * 4 + 1];
      float a2 = As[k][tm * 4 + 2], a3 = As[k][tm * 4 + 3];
      float b0 = Bs[k][tn * 4 + 0], b1 = Bs[k][tn * 4 + 1];
      float b2 = Bs[k][tn * 4 + 2], b3 = Bs[k][tn * 4 + 3];
      acc[0][0] += a0 * b0; acc[0][1] += a0 * b1; acc[0][2] += a0 * b2; acc[0][3] += a0 * b3;
      acc[1][0] += a1 * b0; acc[1][1] += a1 * b1; acc[1][2] += a1 * b2; acc[1][3] += a1 * b3;
      acc[2][0] += a2 * b0; acc[2][1] += a2 * b1; acc[2][2] += a2 * b2; acc[2][3] += a2 * b3;
      acc[3][0] += a3 * b0; acc[3][1] += a3 * b1; acc[3][2] += a3 * b2; acc[3][3] += a3 * b3;
    }
    __syncthreads();
  }
#pragma unroll
  for (int i = 0; i < 4; ++i) {
    const size_t row = (size_t)(M0 + tm * 4 + i);
    float4 v;
    v.x = acc[i][0] + bias[N0 + tn * 4 + 0];
    v.y = acc[i][1] + bias[N0 + tn * 4 + 1];
    v.z = acc[i][2] + bias[N0 + tn * 4 + 2];
    v.w = acc[i][3] + bias[N0 + tn * 4 + 3];
    *(float4*)&C[row * 512 + N0 + tn * 4] = v;
  }
}

// ---------------- Kernel 2: wave-autonomous clique scan --------------------
// 64 blocks x 512 thr = 8 cliques x 8 blocks; clique owns batches [4bg,+4),
// block owns cols [64cg,+64). Lane (kq=lane&15, cp=tid>>4): 2 cols x 32 k;
// W = 64 regs loaded by VOLATILE asm (remat-proof). Round = 2 phases
// (batches {0,1} then {2,3}). Each WAVE independently: pre-issued 4x
// dwordx4 sc1 poll loads (1 RTT, issued a phase early) -> band check ->
// private-LDS stage (lgkmcnt only, NO __syncthreads) -> 128 FMA -> 16-lane
// shfl reduce -> 4 lanes finalize/publish. sc1 = agent scope (IC), the
// r2/r4-proven transport; sc0(=SE scope) abandoned (r3/r8 lessons).
constexpr int NBLK = 64, NTHR = 512;

__device__ __forceinline__ void ld4_issue(const float* p, f32x4& v) {
  asm volatile("global_load_dwordx4 %0, %1, off sc1" : "=v"(v) : "v"(p) : "memory");
}
__device__ __forceinline__ void ldW(const float* p, float& v) {
  asm volatile("global_load_dword %0, %1, off" : "=v"(v) : "v"(p) : "memory");
}
__device__ __forceinline__ void st1(float* p, float v) {
  asm volatile("global_store_dword %0, %1, off sc1" ::"v"(p), "v"(v) : "memory");
}

__global__ __launch_bounds__(NTHR, 2) void rnn_scan(
    float* __restrict__ out, const float* __restrict__ Wrec,
    float* __restrict__ xbuf) {
  __shared__ float hb_all[8][1024];  // per-wave private h stage
  const int blk = blockIdx.x;
  const int bg = blk >> 3, cg = blk & 7;
  const int C0 = cg * 64;
  const int gb0 = bg * 4;
  const int tid = threadIdx.x;
  const int wv = tid >> 6, lane = tid & 63;
  const int kq = lane & 15;       // k-slice id (32 k each)
  const int cp = tid >> 4;        // 0..31: col pair {C0+cp, C0+cp+32}
  const int col0 = C0 + cp, col1 = C0 + cp + 32;
  const int kb = kq * 32;
  const int swz = (kq & 7) << 2;
  const int sg = 4 * lane;        // staging: lane covers slab[j*256+sg .. +4)
  float* hb = hb_all[wv];

  // ---- W into regs via volatile asm loads (cannot be rematerialized) ----
  float w0[32], w1[32];
  {
    const float* p0 = Wrec + (size_t)kb * D + col0;
    const float* p1 = Wrec + (size_t)kb * D + col1;
#pragma unroll
    for (int i = 0; i < 32; ++i) {
      ldW(p0 + (size_t)i * D, w0[i]);
      ldW(p1 + (size_t)i * D, w1[i]);
    }
    asm volatile("s_waitcnt vmcnt(0)" ::: "memory");
  }

  float* xcl = xbuf + (size_t)bg * 4096;  // [parity(2)][batch(4)][512]
  const float OF[4] = {3.f, 9.f, -3.f, -9.f};

  // ---- t = 0: lanes kq<8 handle (s = kq>>1, col = kq&1) -------------------
  if (kq < 8) {
    const int s = kq >> 1;
    const int cc = (kq & 1) ? col1 : col0;
    const size_t o = ((size_t)(gb0 + s) * T) * D + cc;
    const float h = tanhf(out[o]);
    out[o] = h;
    st1(xcl + 0 * 2048 + s * 512 + cc, h + OF[0]);
  }

  // pre-issue r=1 P0 (parity 0, slab ofs 0)
  f32x4 eA[4], eB[4];
#pragma unroll
  for (int j = 0; j < 4; ++j) ld4_issue(xcl + j * 256 + sg, eA[j]);

#define PHASE(EC, EN, S0, NEXTOFS)                                            \
  {                                                                           \
    asm volatile("s_waitcnt vmcnt(0)"                                         \
                 : "+v"(EC[0]), "+v"(EC[1]), "+v"(EC[2]), "+v"(EC[3])         \
                 ::"memory");                                                 \
    bool ok = true;                                                           \
    _Pragma("unroll") for (int j = 0; j < 4; ++j)                             \
      _Pragma("unroll") for (int q = 0; q < 4; ++q)                           \
        ok &= (fabsf(EC[j][q] - offR) < 1.5f);                                \
    if (!ok) {                                                                \
      const float* rp = xcl + pv * 2048 + (S0) * 512;                         \
      do {                                                                    \
        _Pragma("unroll") for (int j = 0; j < 4; ++j)                         \
            ld4_issue(rp + j * 256 + sg, EC[j]);                              \
        asm volatile("s_waitcnt vmcnt(0)"                                     \
                     : "+v"(EC[0]), "+v"(EC[1]), "+v"(EC[2]), "+v"(EC[3])     \
                     ::"memory");                                             \
        ok = true;                                                            \
        _Pragma("unroll") for (int j = 0; j < 4; ++j)                         \
          _Pragma("unroll") for (int q = 0; q < 4; ++q)                       \
            ok &= (fabsf(EC[j][q] - offR) < 1.5f);                            \
      } while (!ok);                                                          \
    }                                                                         \
    _Pragma("unroll") for (int j = 0; j < 4; ++j) {                           \
      const int ix = j * 256 + sg;                                            \
      *(f32x4*)&hb[ix ^ (((ix >> 5) & 7) << 2)] = EC[j] - offR;               \
    }                                                                         \
    _Pragma("unroll") for (int j = 0; j < 4; ++j)                             \
        ld4_issue(xcl + (NEXTOFS) + j * 256 + sg, EN[j]);                     \
    float xwv = 0.f;                                                          \
    int ssel = 0, csel = 0;                                                   \
    if (kq < 4) {                                                             \
      ssel = (S0) + (kq >> 1);                                                \
      csel = (kq & 1) ? col1 : col0;                                          \
      xwv = out[((size_t)(gb0 + ssel) * T + r) * D + csel];                   \
    }                                                                         \
    asm volatile("s_waitcnt lgkmcnt(0)" ::: "memory");                        \
    __builtin_amdgcn_sched_barrier(0);                                        \
    float a00 = 0.f, a01 = 0.f, a10 = 0.f, a11 = 0.f;                         \
    _Pragma("unroll") for (int i4 = 0; i4 < 8; ++i4) {                        \
      const f32x4 h0 = *(const f32x4*)&hb[(kb + 4 * i4) ^ swz];               \
      const f32x4 h1 = *(const f32x4*)&hb[512 + ((kb + 4 * i4) ^ swz)];       \
      _Pragma("unroll") for (int j = 0; j < 4; ++j) {                         \
        a00 += w0[4 * i4 + j] * h0[j];                                        \
        a01 += w1[4 * i4 + j] * h0[j];                                        \
        a10 += w0[4 * i4 + j] * h1[j];                                        \
        a11 += w1[4 * i4 + j] * h1[j];                                        \
      }                                                                       \
    }                                                                         \
    _Pragma("unroll") for (int m = 1; m < 16; m <<= 1) {                      \
      a00 += __shfl_xor(a00, m);                                              \
      a01 += __shfl_xor(a01, m);                                              \
      a10 += __shfl_xor(a10, m);                                              \
      a11 += __shfl_xor(a11, m);                                              \
    }                                                                         \
    if (kq < 4) {                                                             \
      const float av = (kq == 0) ? a00 : (kq == 1) ? a01 : (kq == 2) ? a10 : a11; \
      const float h = tanhf(av + xwv);                                        \
      out[((size_t)(gb0 + ssel) * T + r) * D + csel] = h;                     \
      st1(xcl + pw * 2048 + ssel * 512 + csel, h + offW);                     \
    }                                                                         \
  }

  for (int r = 1; r < T; ++r) {
    const int pv = (r - 1) & 1, pw = r & 1;
    const float offR = OF[(r - 1) & 3], offW = OF[r & 3];
    PHASE(eA, eB, 0, pv * 2048 + 1024)  // P0 (batches 0,1); pre-issue P1
    PHASE(eB, eA, 2, pw * 2048 + 0)     // P1 (batches 2,3); pre-issue next P0
  }
#undef PHASE
}

extern "C" void kernel_launch(void* const* d_in, const int* in_sizes, int n_in,
                              void* d_out, int out_size, void* d_ws, size_t ws_size,
                              hipStream_t stream) {
  const float* x = (const float*)d_in[0];
  const float* W = (const float*)d_in[1];
  const float* Wrec = (const float*)d_in[2];
  const float* bias = (const float*)d_in[3];
  float* out = (float*)d_out;

  // xw + bias straight into d_out (row = b*T+t matches [B][T][D]).
  xw_gemm<<<dim3(D / 64, (B * T) / 64), 256, 0, stream>>>(x, W, bias, out);

  // xbuf: 8 cliques x 2 parities x 4 batches x 512 floats = 128 KB.
  // Zeroed every launch (zero is in no band) -> deterministic replays.
  hipMemsetAsync(d_ws, 0, 131072, stream);
  float* xbuf = (float*)d_ws;

  void* args[] = {(void*)&out, (void*)&Wrec, (void*)&xbuf};
  hipLaunchCooperativeKernel(reinterpret_cast<void*>(rnn_scan), dim3(NBLK),
                             dim3(NTHR), args, 0, stream);
}